// Round 1
// baseline (444.965 us; speedup 1.0000x reference)
//
#include <hip/hip_runtime.h>
#include <hip/hip_bf16.h>

namespace {
constexpr int Bn = 4, Cn = 32, Dn = 48, Hn = 64, Wn = 128;
constexpr int HQ = 32, WQ = 64;
constexpr int NPB = Dn * HQ * WQ;        // 98304 positions per batch (pooled)
constexpr int PERB = Cn * Dn * Hn * Wn;  // 12582912 elements per batch (full)
constexpr int NS = 128;                  // Hs*Ws keys
constexpr int En = 12;                   // dqk == dv
constexpr int CF = 256;
constexpr float EPS = 1e-5f;
constexpr float SQK = 0.2886751345948129f;  // 1/sqrt(12)

// workspace offsets (in floats)
constexpr size_t OFF_P    = 0;                                   // 12582912
constexpr size_t OFF_Z    = OFF_P + (size_t)Bn * Cn * NPB;       // 12582912
constexpr size_t OFF_PART = OFF_Z + (size_t)Bn * Cn * NPB;       // 4*12288 float2 = 98304 floats
constexpr size_t OFF_S1   = OFF_PART + 98304;                    // 4 float2
constexpr size_t OFF_S2   = OFF_S1 + 8;
constexpr size_t OFF_KB   = OFF_S2 + 8;                          // 4*128*12
constexpr size_t OFF_VB   = OFF_KB + (size_t)Bn * NS * En;
constexpr size_t OFF_QW   = OFF_VB + (size_t)Bn * NS * En;       // 4*12*32
constexpr size_t OFF_QB   = OFF_QW + (size_t)Bn * En * Cn;       // 4*12
}  // namespace

__device__ inline float bf16_rne(float x) {
    unsigned u = __float_as_uint(x);
    u = (u + 0x7fffu + ((u >> 16) & 1u)) & 0xffff0000u;
    return __uint_as_float(u);
}

// ---------------- K1: pooled cost + GN-in partial stats ----------------
__global__ __launch_bounds__(256) void k_pool_stats(const float* __restrict__ cost,
                                                    float* __restrict__ P,
                                                    float2* __restrict__ part) {
    int b = blockIdx.y;
    int p = blockIdx.x * 256 + threadIdx.x;  // 0 .. 3145727  (c,n)
    int c = p / NPB;
    int n = p - c * NPB;
    int d = n >> 11;
    int r = n & 2047;
    int hq = r >> 6, wq = r & 63;
    const float* src = cost + ((size_t)((b * Cn + c) * Dn + d)) * (Hn * Wn) + (hq * 2) * Wn + wq * 2;
    float2 t0 = *reinterpret_cast<const float2*>(src);
    float2 t1 = *reinterpret_cast<const float2*>(src + Wn);
    float s  = t0.x + t0.y + t1.x + t1.y;
    float ss = t0.x * t0.x + t0.y * t0.y + t1.x * t1.x + t1.y * t1.y;
    P[(size_t)(b * Cn + c) * NPB + n] = 0.25f * s;

    __shared__ float ra[256], rb[256];
    int tid = threadIdx.x;
    ra[tid] = s; rb[tid] = ss;
    __syncthreads();
    for (int st = 128; st > 0; st >>= 1) {
        if (tid < st) { ra[tid] += ra[tid + st]; rb[tid] += rb[tid + st]; }
        __syncthreads();
    }
    if (tid == 0) part[b * 12288 + blockIdx.x] = make_float2(ra[0], rb[0]);
}

// ---------------- finalize per-batch mean / rsqrt(var+eps) ----------------
__global__ __launch_bounds__(256) void k_finalize(const float2* __restrict__ part, int npart,
                                                  float inv_count, float2* __restrict__ stats) {
    int b = blockIdx.x;
    int tid = threadIdx.x;
    float s = 0.f, ss = 0.f;
    for (int i = tid; i < npart; i += 256) {
        float2 v = part[b * npart + i];
        s += v.x; ss += v.y;
    }
    __shared__ float ra[256], rb[256];
    ra[tid] = s; rb[tid] = ss;
    __syncthreads();
    for (int st = 128; st > 0; st >>= 1) {
        if (tid < st) { ra[tid] += ra[tid + st]; rb[tid] += rb[tid + st]; }
        __syncthreads();
    }
    if (tid == 0) {
        float m = ra[0] * inv_count;
        float var = rb[0] * inv_count - m * m;
        stats[b] = make_float2(m, rsqrtf(var + EPS));
    }
}

// ---------------- K2: K/V from feat_s4, effective q weights ----------------
__global__ __launch_bounds__(128) void k_kv_qw(const float* __restrict__ feat,
                                               const float* __restrict__ w_k,
                                               const float* __restrict__ w_v,
                                               const float* __restrict__ w_q,
                                               const float* __restrict__ gniw,
                                               const float* __restrict__ gnib,
                                               const float2* __restrict__ stats1,
                                               float* __restrict__ KB, float* __restrict__ VB,
                                               float* __restrict__ QW, float* __restrict__ QB) {
    __shared__ float wk_s[En * CF], wv_s[En * CF];
    int b = blockIdx.x;
    int tid = threadIdx.x;  // 0..127  == key index s
    for (int i = tid; i < En * CF; i += 128) { wk_s[i] = w_k[i]; wv_s[i] = w_v[i]; }
    __syncthreads();

    float kk[En], vv[En];
#pragma unroll
    for (int e = 0; e < En; ++e) { kk[e] = 0.f; vv[e] = 0.f; }
    for (int c = 0; c < CF; ++c) {
        float f = feat[(size_t)(b * CF + c) * NS + tid];
#pragma unroll
        for (int e = 0; e < En; ++e) {
            kk[e] += wk_s[e * CF + c] * f;
            vv[e] += wv_s[e * CF + c] * f;
        }
    }
#pragma unroll
    for (int e = 0; e < En; ++e) {
        KB[(size_t)(b * NS + tid) * En + e] = kk[e];
        VB[(size_t)(b * NS + tid) * En + e] = vv[e];
    }

    float2 st = stats1[b];
    float m = st.x, rs = st.y;
    for (int t = tid; t < En * Cn; t += 128) {
        int c = t & 31;
        QW[b * En * Cn + t] = SQK * w_q[t] * (rs * gniw[c]);
    }
    if (tid < En) {
        float acc = 0.f;
        for (int c = 0; c < Cn; ++c)
            acc += w_q[tid * Cn + c] * (gnib[c] - m * rs * gniw[c]);
        QB[b * En + tid] = SQK * acc;
    }
}

// ---------------- K3: attention + output projection ----------------
__global__ __launch_bounds__(256) void k_attn(const float* __restrict__ Pp,
                                              const float* __restrict__ KB,
                                              const float* __restrict__ VB,
                                              const float* __restrict__ QW,
                                              const float* __restrict__ QB,
                                              const float* __restrict__ w_out,
                                              float* __restrict__ Z) {
    __shared__ float Ks[NS * En], Vs[NS * En], QWs[En * Cn], WOs[Cn * En], QBs[En];
    int b = blockIdx.y;
    int tid = threadIdx.x;
    for (int i = tid; i < NS * En; i += 256) { Ks[i] = KB[(size_t)b * NS * En + i]; Vs[i] = VB[(size_t)b * NS * En + i]; }
    for (int i = tid; i < En * Cn; i += 256) { QWs[i] = QW[b * En * Cn + i]; WOs[i] = w_out[i]; }
    if (tid < En) QBs[tid] = QB[b * En + tid];
    __syncthreads();

    int n = blockIdx.x * 256 + tid;  // < 98304
    float q[En];
#pragma unroll
    for (int e = 0; e < En; ++e) q[e] = QBs[e];
    for (int c = 0; c < Cn; ++c) {
        float xv = Pp[(size_t)(b * Cn + c) * NPB + n];
#pragma unroll
        for (int e = 0; e < En; ++e) q[e] += QWs[e * Cn + c] * xv;
    }
    float mx = -1e30f;
    for (int s = 0; s < NS; ++s) {
        float dot = 0.f;
#pragma unroll
        for (int e = 0; e < En; ++e) dot += q[e] * Ks[s * En + e];
        mx = fmaxf(mx, dot);
    }
    float l = 0.f;
    float o[En];
#pragma unroll
    for (int e = 0; e < En; ++e) o[e] = 0.f;
    for (int s = 0; s < NS; ++s) {
        float dot = 0.f;
#pragma unroll
        for (int e = 0; e < En; ++e) dot += q[e] * Ks[s * En + e];
        float pe = __expf(dot - mx);
        l += pe;
#pragma unroll
        for (int e = 0; e < En; ++e) o[e] += pe * Vs[s * En + e];
    }
    float inv = 1.0f / l;
    for (int c = 0; c < Cn; ++c) {
        float z = 0.f;
#pragma unroll
        for (int e = 0; e < En; ++e) z += WOs[c * En + e] * o[e];
        Z[(size_t)(b * Cn + c) * NPB + n] = z * inv;
    }
}

// ---------------- upsample (bilinear in H,W; depth identity) ----------------
__device__ inline float upsample_z(const float* __restrict__ zp, int h, int w) {
    // zp points at Z[b][c][d][0][0]
    int h0 = (h - 1) >> 1;               // floor((h-0.5)/2 - eps): even->j-1, odd->j
    float wh0 = (h & 1) ? 0.75f : 0.25f;
    int w0 = (w - 1) >> 1;
    float ww0 = (w & 1) ? 0.75f : 0.25f;
    int h1 = h0 + 1, w1 = w0 + 1;
    h0 = max(h0, 0); h1 = min(h1, HQ - 1);
    w0 = max(w0, 0); w1 = min(w1, WQ - 1);
    float z00 = zp[h0 * WQ + w0], z01 = zp[h0 * WQ + w1];
    float z10 = zp[h1 * WQ + w0], z11 = zp[h1 * WQ + w1];
    float wh1 = 1.0f - wh0, ww1 = 1.0f - ww0;
    return wh0 * (ww0 * z00 + ww1 * z01) + wh1 * (ww0 * z10 + ww1 * z11);
}

// ---------------- K4a: stats of y = cost + gamma*bf16(up(Z)) ----------------
__global__ __launch_bounds__(256) void k_ystats(const float* __restrict__ cost,
                                                const float* __restrict__ Z,
                                                const float* __restrict__ gamma_p,
                                                float2* __restrict__ part) {
    int b = blockIdx.y;
    int tid = threadIdx.x;
    int quad = blockIdx.x * 256 + tid;  // 0 .. 3145727
    int idx = quad * 4;
    int c = idx / (Dn * Hn * Wn);
    int r = idx - c * (Dn * Hn * Wn);
    int d = r >> 13;
    int r2 = r & 8191;
    int h = r2 >> 7, w4 = r2 & 127;
    float g = gamma_p[0];
    const float* zp = Z + (size_t)(b * Cn + c) * NPB + d * (HQ * WQ);
    float4 cv = *reinterpret_cast<const float4*>(cost + (size_t)b * PERB + idx);
    float y0 = cv.x + g * bf16_rne(upsample_z(zp, h, w4 + 0));
    float y1 = cv.y + g * bf16_rne(upsample_z(zp, h, w4 + 1));
    float y2 = cv.z + g * bf16_rne(upsample_z(zp, h, w4 + 2));
    float y3 = cv.w + g * bf16_rne(upsample_z(zp, h, w4 + 3));
    float s = y0 + y1 + y2 + y3;
    float ss = y0 * y0 + y1 * y1 + y2 * y2 + y3 * y3;

    __shared__ float ra[256], rb[256];
    ra[tid] = s; rb[tid] = ss;
    __syncthreads();
    for (int st = 128; st > 0; st >>= 1) {
        if (tid < st) { ra[tid] += ra[tid + st]; rb[tid] += rb[tid + st]; }
        __syncthreads();
    }
    if (tid == 0) part[b * 12288 + blockIdx.x] = make_float2(ra[0], rb[0]);
}

// ---------------- K4c: final GroupNorm write ----------------
__global__ __launch_bounds__(256) void k_final(const float* __restrict__ cost,
                                               const float* __restrict__ Z,
                                               const float* __restrict__ gamma_p,
                                               const float2* __restrict__ stats2,
                                               const float* __restrict__ gow,
                                               const float* __restrict__ gob,
                                               float* __restrict__ out) {
    int b = blockIdx.y;
    int tid = threadIdx.x;
    int quad = blockIdx.x * 256 + tid;
    int idx = quad * 4;
    int c = idx / (Dn * Hn * Wn);
    int r = idx - c * (Dn * Hn * Wn);
    int d = r >> 13;
    int r2 = r & 8191;
    int h = r2 >> 7, w4 = r2 & 127;
    float g = gamma_p[0];
    float2 st = stats2[b];
    float m = st.x, rs = st.y;
    float sc = rs * gow[c];
    float bi = gob[c];
    const float* zp = Z + (size_t)(b * Cn + c) * NPB + d * (HQ * WQ);
    float4 cv = *reinterpret_cast<const float4*>(cost + (size_t)b * PERB + idx);
    float y0 = cv.x + g * bf16_rne(upsample_z(zp, h, w4 + 0));
    float y1 = cv.y + g * bf16_rne(upsample_z(zp, h, w4 + 1));
    float y2 = cv.z + g * bf16_rne(upsample_z(zp, h, w4 + 2));
    float y3 = cv.w + g * bf16_rne(upsample_z(zp, h, w4 + 3));
    float4 ov;
    ov.x = (y0 - m) * sc + bi;
    ov.y = (y1 - m) * sc + bi;
    ov.z = (y2 - m) * sc + bi;
    ov.w = (y3 - m) * sc + bi;
    *reinterpret_cast<float4*>(out + (size_t)b * PERB + idx) = ov;
}

extern "C" void kernel_launch(void* const* d_in, const int* in_sizes, int n_in,
                              void* d_out, int out_size, void* d_ws, size_t ws_size,
                              hipStream_t stream) {
    const float* cost  = (const float*)d_in[0];
    const float* feat  = (const float*)d_in[1];
    const float* w_q   = (const float*)d_in[2];
    const float* w_k   = (const float*)d_in[3];
    const float* w_v   = (const float*)d_in[4];
    const float* w_out = (const float*)d_in[5];
    const float* gniw  = (const float*)d_in[6];
    const float* gnib  = (const float*)d_in[7];
    const float* gow   = (const float*)d_in[8];
    const float* gob   = (const float*)d_in[9];
    const float* gamma = (const float*)d_in[10];

    float* ws = (float*)d_ws;
    float* out = (float*)d_out;

    float* P   = ws + OFF_P;
    float* Z   = ws + OFF_Z;
    float2* part = (float2*)(ws + OFF_PART);
    float2* s1 = (float2*)(ws + OFF_S1);
    float2* s2 = (float2*)(ws + OFF_S2);
    float* KB  = ws + OFF_KB;
    float* VB  = ws + OFF_VB;
    float* QW  = ws + OFF_QW;
    float* QB  = ws + OFF_QB;

    float inv_count = 1.0f / (float)PERB;

    k_pool_stats<<<dim3(12288, Bn), 256, 0, stream>>>(cost, P, part);
    k_finalize<<<Bn, 256, 0, stream>>>(part, 12288, inv_count, s1);
    k_kv_qw<<<Bn, 128, 0, stream>>>(feat, w_k, w_v, w_q, gniw, gnib, s1, KB, VB, QW, QB);
    k_attn<<<dim3(NPB / 256, Bn), 256, 0, stream>>>(P, KB, VB, QW, QB, w_out, Z);
    k_ystats<<<dim3(12288, Bn), 256, 0, stream>>>(cost, Z, gamma, part);
    k_finalize<<<Bn, 256, 0, stream>>>(part, 12288, inv_count, s2);
    k_final<<<dim3(12288, Bn), 256, 0, stream>>>(cost, Z, gamma, s2, gow, gob, out);
}

// Round 2
// 223.141 us; speedup vs baseline: 1.9941x; 1.9941x over previous
//
#include <hip/hip_runtime.h>
#include <hip/hip_bf16.h>

namespace {
constexpr int Bn = 4, Cn = 32, Dn = 48, Hn = 64, Wn = 128;
constexpr int HQ = 32, WQ = 64;
constexpr int NPB = Dn * HQ * WQ;        // 98304 pooled positions per batch
constexpr int PERB = Cn * Dn * Hn * Wn;  // 12582912 elements per batch
constexpr int NS = 128;
constexpr int En = 12;
constexpr float EPS = 1e-5f;
constexpr float SQK = 0.2886751345948129f;  // 1/sqrt(12)

// workspace offsets (in floats)
constexpr size_t OFF_QR   = 0;                                    // 4*12*98304
constexpr size_t OFF_Z    = OFF_QR + (size_t)Bn * En * NPB;       // 4*32*98304
constexpr size_t OFF_PKV  = OFF_Z + (size_t)Bn * Cn * NPB;        // 4*16*24*128
constexpr size_t OFF_PART = OFF_PKV + (size_t)Bn * 16 * 24 * 128; // 4*2048 float2
constexpr size_t OFF_S1   = OFF_PART + 16384;
constexpr size_t OFF_S2   = OFF_S1 + 8;
constexpr size_t OFF_KB   = OFF_S2 + 8;                           // 4*128*12
constexpr size_t OFF_VB   = OFF_KB + (size_t)Bn * NS * En;
constexpr size_t OFF_QB   = OFF_VB + (size_t)Bn * NS * En;        // 4*12
constexpr size_t OFF_KS   = OFF_QB + 48;                          // 4
}  // namespace

__device__ inline float bf16_rne(float x) {
    unsigned u = __float_as_uint(x);
    u = (u + 0x7fffu + ((u >> 16) & 1u)) & 0xffff0000u;
    return __uint_as_float(u);
}

// block = 256 threads (4 waves). Shuffle-reduce (s, ss), thread 0 stores.
__device__ inline void block_reduce_store(float s, float ss, float2* dst) {
#pragma unroll
    for (int off = 32; off > 0; off >>= 1) {
        s += __shfl_down(s, off, 64);
        ss += __shfl_down(ss, off, 64);
    }
    __shared__ float as[4], bs[4];
    int lane = threadIdx.x & 63, w = threadIdx.x >> 6;
    if (lane == 0) { as[w] = s; bs[w] = ss; }
    __syncthreads();
    if (threadIdx.x == 0)
        *dst = make_float2(as[0] + as[1] + as[2] + as[3], bs[0] + bs[1] + bs[2] + bs[3]);
}

// ---------- K1: pool + q-raw projection + GN-in partial stats ----------
// qraw[e] = sum_c (w_q[e,c]*gniw[c]) * xpool_c   (rs/bias folded in later)
__global__ __launch_bounds__(256) void k1_pool_q_stats(const float* __restrict__ cost,
                                                       const float* __restrict__ w_q,
                                                       const float* __restrict__ gniw,
                                                       float* __restrict__ qr,
                                                       float2* __restrict__ part) {
    __shared__ float wqg[En * Cn];
    int b = blockIdx.y, tid = threadIdx.x;
    for (int i = tid; i < En * Cn; i += 256) wqg[i] = w_q[i] * gniw[i & 31];
    __syncthreads();
    int n = blockIdx.x * 256 + tid;
    int d = n >> 11, r = n & 2047, hq = r >> 6, wq = r & 63;
    const float* base = cost + (size_t)b * PERB + (size_t)d * (Hn * Wn) + (hq * 2) * Wn + wq * 2;
    float s = 0.f, ss = 0.f;
    float q[En];
#pragma unroll
    for (int e = 0; e < En; ++e) q[e] = 0.f;
#pragma unroll 4
    for (int c = 0; c < Cn; ++c) {
        const float* src = base + (size_t)c * (Dn * Hn * Wn);
        float2 t0 = *reinterpret_cast<const float2*>(src);
        float2 t1 = *reinterpret_cast<const float2*>(src + Wn);
        float ps = t0.x + t0.y + t1.x + t1.y;
        s += ps;
        ss += t0.x * t0.x + t0.y * t0.y + t1.x * t1.x + t1.y * t1.y;
        float pv = 0.25f * ps;
#pragma unroll
        for (int e = 0; e < En; ++e) q[e] += wqg[e * Cn + c] * pv;
    }
#pragma unroll
    for (int e = 0; e < En; ++e) qr[(size_t)(b * En + e) * NPB + n] = q[e];
    block_reduce_store(s, ss, &part[b * 2048 + blockIdx.x]);
}

// ---------- finalize per-batch mean / rsqrt(var+eps) ----------
__global__ __launch_bounds__(256) void k_finalize(const float2* __restrict__ part, int npart,
                                                  float inv_count, float2* __restrict__ stats) {
    int b = blockIdx.x, tid = threadIdx.x;
    float s = 0.f, ss = 0.f;
    for (int i = tid; i < npart; i += 256) {
        float2 v = part[b * 2048 + i];
        s += v.x; ss += v.y;
    }
#pragma unroll
    for (int off = 32; off > 0; off >>= 1) {
        s += __shfl_down(s, off, 64);
        ss += __shfl_down(ss, off, 64);
    }
    __shared__ float as[4], bs[4];
    int lane = tid & 63, w = tid >> 6;
    if (lane == 0) { as[w] = s; bs[w] = ss; }
    __syncthreads();
    if (tid == 0) {
        float m = (as[0] + as[1] + as[2] + as[3]) * inv_count;
        float var = (bs[0] + bs[1] + bs[2] + bs[3]) * inv_count - m * m;
        stats[b] = make_float2(m, rsqrtf(var + EPS));
    }
}

// ---------- K/V partials: grid (Bn, 16 chunks), block 128 (s) ----------
__global__ __launch_bounds__(128) void k_kv_part(const float* __restrict__ feat,
                                                 const float* __restrict__ w_k,
                                                 const float* __restrict__ w_v,
                                                 float* __restrict__ pkv) {
    int b = blockIdx.x, ch = blockIdx.y, s = threadIdx.x;
    __shared__ float wks[En * 16], wvs[En * 16];
    for (int i = s; i < En * 16; i += 128) {
        int e = i >> 4, c = i & 15;
        wks[i] = w_k[e * 256 + ch * 16 + c];
        wvs[i] = w_v[e * 256 + ch * 16 + c];
    }
    __syncthreads();
    float f[16];
#pragma unroll
    for (int j = 0; j < 16; ++j) f[j] = feat[(size_t)(b * 256 + ch * 16 + j) * NS + s];
    float kk[En], vv[En];
#pragma unroll
    for (int e = 0; e < En; ++e) { kk[e] = 0.f; vv[e] = 0.f; }
#pragma unroll
    for (int j = 0; j < 16; ++j) {
#pragma unroll
        for (int e = 0; e < En; ++e) {
            kk[e] += wks[e * 16 + j] * f[j];
            vv[e] += wvs[e * 16 + j] * f[j];
        }
    }
#pragma unroll
    for (int e = 0; e < En; ++e) {
        pkv[((size_t)(b * 16 + ch) * 24 + e) * 128 + s] = kk[e];
        pkv[((size_t)(b * 16 + ch) * 24 + 12 + e) * 128 + s] = vv[e];
    }
}

// ---------- K/V reduce + k-norm max + q bias ----------
__global__ __launch_bounds__(256) void k_kv2(const float* __restrict__ pkv,
                                             const float* __restrict__ w_q,
                                             const float* __restrict__ gniw,
                                             const float* __restrict__ gnib,
                                             const float2* __restrict__ stats1,
                                             float* __restrict__ KB, float* __restrict__ VB,
                                             float* __restrict__ QB, float* __restrict__ kscale) {
    int b = blockIdx.x, tid = threadIdx.x;
    __shared__ float wmax[2];
    if (tid < 128) {
        int s = tid;
        float kk[En], vv[En];
#pragma unroll
        for (int e = 0; e < En; ++e) { kk[e] = 0.f; vv[e] = 0.f; }
        for (int ch = 0; ch < 16; ++ch) {
            const float* p = pkv + ((size_t)(b * 16 + ch) * 24) * 128 + s;
#pragma unroll
            for (int e = 0; e < En; ++e) {
                kk[e] += p[e * 128];
                vv[e] += p[(12 + e) * 128];
            }
        }
        float n2 = 0.f;
#pragma unroll
        for (int e = 0; e < En; ++e) {
            KB[(size_t)(b * NS + s) * En + e] = kk[e];
            VB[(size_t)(b * NS + s) * En + e] = vv[e];
            n2 += kk[e] * kk[e];
        }
        float nn = sqrtf(n2);
#pragma unroll
        for (int off = 32; off > 0; off >>= 1) nn = fmaxf(nn, __shfl_down(nn, off, 64));
        if ((tid & 63) == 0) wmax[tid >> 6] = nn;
    }
    __syncthreads();
    if (tid == 0) kscale[b] = fmaxf(wmax[0], wmax[1]);
    float2 st = stats1[b];
    if (tid < En) {
        float acc = 0.f;
        for (int c = 0; c < Cn; ++c)
            acc += w_q[tid * Cn + c] * (gnib[c] - st.x * st.y * gniw[c]);
        QB[b * En + tid] = SQK * acc;
    }
}

// ---------- attention (one-pass, UB-shifted softmax) + out projection ----------
__global__ __launch_bounds__(256) void k_attn(const float* __restrict__ qr,
                                              const float* __restrict__ KB,
                                              const float* __restrict__ VB,
                                              const float* __restrict__ QB,
                                              const float* __restrict__ kscale,
                                              const float2* __restrict__ stats1,
                                              const float* __restrict__ w_out,
                                              float* __restrict__ Z) {
    __shared__ float Ks[NS * En], Vs[NS * En], WOs[Cn * En], QBs[En];
    int b = blockIdx.y, tid = threadIdx.x;
    for (int i = tid; i < NS * En; i += 256) {
        Ks[i] = KB[(size_t)b * NS * En + i];
        Vs[i] = VB[(size_t)b * NS * En + i];
    }
    for (int i = tid; i < Cn * En; i += 256) WOs[i] = w_out[i];
    if (tid < En) QBs[tid] = QB[b * En + tid];
    __syncthreads();
    int n = blockIdx.x * 256 + tid;
    float qsc = stats1[b].y * SQK;
    float q[En];
    float qn2 = 0.f;
#pragma unroll
    for (int e = 0; e < En; ++e) {
        q[e] = qsc * qr[(size_t)(b * En + e) * NPB + n] + QBs[e];
        qn2 += q[e] * q[e];
    }
    float ub = sqrtf(qn2) * kscale[b];  // >= max logit (Cauchy-Schwarz)
    float l = 0.f;
    float o[En];
#pragma unroll
    for (int e = 0; e < En; ++e) o[e] = 0.f;
    for (int s = 0; s < NS; ++s) {
        float dot = 0.f;
#pragma unroll
        for (int e = 0; e < En; ++e) dot += q[e] * Ks[s * En + e];
        float pe = __expf(dot - ub);
        l += pe;
#pragma unroll
        for (int e = 0; e < En; ++e) o[e] += pe * Vs[s * En + e];
    }
    float inv = 1.0f / l;
    for (int c = 0; c < Cn; ++c) {
        float z = 0.f;
#pragma unroll
        for (int e = 0; e < En; ++e) z += WOs[c * En + e] * o[e];
        Z[(size_t)(b * Cn + c) * NPB + n] = z * inv;
    }
}

// ---------- upsample weights (half-pixel, scale 2) ----------
// shared slice kernels: one block per (b,c,d); Z slice 32x64 in LDS.

__global__ __launch_bounds__(256) void k_ystats(const float* __restrict__ cost,
                                                const float* __restrict__ Z,
                                                const float* __restrict__ gamma_p,
                                                float2* __restrict__ part) {
    int blk = blockIdx.x;  // ((b*32+c)*48+d)
    __shared__ float zs[HQ * WQ];
    int tid = threadIdx.x;
    const float* zsrc = Z + (size_t)blk * (HQ * WQ);
    const float* csrc = cost + (size_t)blk * (Hn * Wn);
    for (int i = tid; i < HQ * WQ / 4; i += 256)
        reinterpret_cast<float4*>(zs)[i] = reinterpret_cast<const float4*>(zsrc)[i];
    __syncthreads();
    float g = gamma_p[0];
    float s = 0.f, ss = 0.f;
#pragma unroll
    for (int i = 0; i < 8; ++i) {
        int qd = tid + 256 * i;                 // quad index 0..2047
        int h = qd >> 5, w4 = (qd & 31) << 2;
        float4 cv = reinterpret_cast<const float4*>(csrc)[qd];
        int h0 = (h - 1) >> 1;
        float wh0 = (h & 1) ? 0.75f : 0.25f;
        int h1 = h0 + 1;
        h0 = max(h0, 0); h1 = min(h1, HQ - 1);
        const float* r0 = zs + h0 * WQ;
        const float* r1 = zs + h1 * WQ;
        float cvv[4] = {cv.x, cv.y, cv.z, cv.w};
#pragma unroll
        for (int j = 0; j < 4; ++j) {
            int w = w4 + j;
            int w0 = (w - 1) >> 1;
            float ww0 = (w & 1) ? 0.75f : 0.25f;
            int w1 = w0 + 1;
            w0 = max(w0, 0); w1 = min(w1, WQ - 1);
            float u = wh0 * (ww0 * r0[w0] + (1.f - ww0) * r0[w1]) +
                      (1.f - wh0) * (ww0 * r1[w0] + (1.f - ww0) * r1[w1]);
            float y = cvv[j] + g * bf16_rne(u);
            s += y; ss += y * y;
        }
    }
    int b = blk / (Cn * Dn);
    block_reduce_store(s, ss, &part[b * 2048 + (blk % (Cn * Dn))]);
}

__global__ __launch_bounds__(256) void k_final(const float* __restrict__ cost,
                                               const float* __restrict__ Z,
                                               const float* __restrict__ gamma_p,
                                               const float2* __restrict__ stats2,
                                               const float* __restrict__ gow,
                                               const float* __restrict__ gob,
                                               float* __restrict__ out) {
    int blk = blockIdx.x;
    __shared__ float zs[HQ * WQ];
    int tid = threadIdx.x;
    const float* zsrc = Z + (size_t)blk * (HQ * WQ);
    const float* csrc = cost + (size_t)blk * (Hn * Wn);
    float* dsto = out + (size_t)blk * (Hn * Wn);
    for (int i = tid; i < HQ * WQ / 4; i += 256)
        reinterpret_cast<float4*>(zs)[i] = reinterpret_cast<const float4*>(zsrc)[i];
    __syncthreads();
    int b = blk / (Cn * Dn);
    int c = (blk / Dn) % Cn;
    float g = gamma_p[0];
    float2 st = stats2[b];
    float m = st.x, sc = st.y * gow[c], bi = gob[c];
#pragma unroll
    for (int i = 0; i < 8; ++i) {
        int qd = tid + 256 * i;
        int h = qd >> 5, w4 = (qd & 31) << 2;
        float4 cv = reinterpret_cast<const float4*>(csrc)[qd];
        int h0 = (h - 1) >> 1;
        float wh0 = (h & 1) ? 0.75f : 0.25f;
        int h1 = h0 + 1;
        h0 = max(h0, 0); h1 = min(h1, HQ - 1);
        const float* r0 = zs + h0 * WQ;
        const float* r1 = zs + h1 * WQ;
        float cvv[4] = {cv.x, cv.y, cv.z, cv.w};
        float4 ov;
        float* ovp = &ov.x;
#pragma unroll
        for (int j = 0; j < 4; ++j) {
            int w = w4 + j;
            int w0 = (w - 1) >> 1;
            float ww0 = (w & 1) ? 0.75f : 0.25f;
            int w1 = w0 + 1;
            w0 = max(w0, 0); w1 = min(w1, WQ - 1);
            float u = wh0 * (ww0 * r0[w0] + (1.f - ww0) * r0[w1]) +
                      (1.f - wh0) * (ww0 * r1[w0] + (1.f - ww0) * r1[w1]);
            float y = cvv[j] + g * bf16_rne(u);
            ovp[j] = (y - m) * sc + bi;
        }
        reinterpret_cast<float4*>(dsto)[qd] = ov;
    }
}

extern "C" void kernel_launch(void* const* d_in, const int* in_sizes, int n_in,
                              void* d_out, int out_size, void* d_ws, size_t ws_size,
                              hipStream_t stream) {
    const float* cost  = (const float*)d_in[0];
    const float* feat  = (const float*)d_in[1];
    const float* w_q   = (const float*)d_in[2];
    const float* w_k   = (const float*)d_in[3];
    const float* w_v   = (const float*)d_in[4];
    const float* w_out = (const float*)d_in[5];
    const float* gniw  = (const float*)d_in[6];
    const float* gnib  = (const float*)d_in[7];
    const float* gow   = (const float*)d_in[8];
    const float* gob   = (const float*)d_in[9];
    const float* gamma = (const float*)d_in[10];

    float* ws = (float*)d_ws;
    float* outp = (float*)d_out;

    float* QR  = ws + OFF_QR;
    float* Z   = ws + OFF_Z;
    float* PKV = ws + OFF_PKV;
    float2* part = (float2*)(ws + OFF_PART);
    float2* s1 = (float2*)(ws + OFF_S1);
    float2* s2 = (float2*)(ws + OFF_S2);
    float* KB  = ws + OFF_KB;
    float* VB  = ws + OFF_VB;
    float* QB  = ws + OFF_QB;
    float* KS  = ws + OFF_KS;

    float inv_count = 1.0f / (float)PERB;

    k_kv_part<<<dim3(Bn, 16), 128, 0, stream>>>(feat, w_k, w_v, PKV);
    k1_pool_q_stats<<<dim3(NPB / 256, Bn), 256, 0, stream>>>(cost, w_q, gniw, QR, part);
    k_finalize<<<Bn, 256, 0, stream>>>(part, NPB / 256, inv_count, s1);
    k_kv2<<<Bn, 256, 0, stream>>>(PKV, w_q, gniw, gnib, s1, KB, VB, QB, KS);
    k_attn<<<dim3(NPB / 256, Bn), 256, 0, stream>>>(QR, KB, VB, QB, KS, s1, w_out, Z);
    k_ystats<<<Bn * Cn * Dn, 256, 0, stream>>>(cost, Z, gamma, part);
    k_finalize<<<Bn, 256, 0, stream>>>(part, Cn * Dn, inv_count, s2);
    k_final<<<Bn * Cn * Dn, 256, 0, stream>>>(cost, Z, gamma, s2, gow, gob, outp);
}

// Round 4
// 198.530 us; speedup vs baseline: 2.2413x; 1.1240x over previous
//
#include <hip/hip_runtime.h>

typedef float f4v __attribute__((ext_vector_type(4)));

namespace {
constexpr int Bn = 4, Cn = 32, Dn = 48, Hn = 64, Wn = 128;
constexpr int HQ = 32, WQ = 64;
constexpr int NPB = Dn * HQ * WQ;   // 98304 pooled positions / batch
constexpr int DHW = Dn * Hn * Wn;   // 393216
constexpr int PERB = Cn * DHW;      // 12582912 elements / batch
constexpr int NS = 128, En = 12;
constexpr float EPS = 1e-5f;
constexpr float SQK = 0.2886751345948129f;  // 1/sqrt(12)

// workspace float offsets
constexpr size_t OFF_Z    = 0;                      // ushort[4*32*98304] -> 6291456 floats
constexpr size_t OFF_QR   = 6291456;                // ushort[4*12*98304] -> 2359296 floats
constexpr size_t OFF_P1   = OFF_QR + 2359296;       // float2[4*2048] -> 16384 floats
constexpr size_t OFF_P2   = OFF_P1 + 16384;         // float2[4*1536] -> 12288 floats
constexpr size_t OFF_ST1  = OFF_P2 + 12288;         // float2[4]
constexpr size_t OFF_ST2  = OFF_ST1 + 8;
constexpr size_t OFF_KB   = OFF_ST2 + 8;            // 4*128*12
constexpr size_t OFF_VB   = OFF_KB + 6144;
constexpr size_t OFF_KS   = OFF_VB + 6144;          // 4
constexpr size_t OFF_PKV  = OFF_KS + 4;             // 4*16*24*128 = 196608
}  // namespace

__device__ inline unsigned short bf16b(float x) {
    unsigned u = __float_as_uint(x);
    return (unsigned short)((u + 0x7fffu + ((u >> 16) & 1u)) >> 16);
}
__device__ inline float b2f(unsigned short h) { return __uint_as_float(((unsigned)h) << 16); }
__device__ inline float bf16_rne(float x) {
    unsigned u = __float_as_uint(x);
    u = (u + 0x7fffu + ((u >> 16) & 1u)) & 0xffff0000u;
    return __uint_as_float(u);
}

__device__ inline float2 block_red2(float s, float ss) {
#pragma unroll
    for (int off = 32; off; off >>= 1) {
        s += __shfl_down(s, off, 64);
        ss += __shfl_down(ss, off, 64);
    }
    __shared__ float red[8];
    int lane = threadIdx.x & 63, w = threadIdx.x >> 6;
    if (!lane) { red[w] = s; red[4 + w] = ss; }
    __syncthreads();
    float2 r = make_float2(red[0] + red[1] + red[2] + red[3],
                           red[4] + red[5] + red[6] + red[7]);
    __syncthreads();
    return r;
}

// ---------- K1: pool + qraw(bf16) + GN-in partial stats + (64 blocks) K/V partials ----------
__global__ __launch_bounds__(256) void k1_pool(const float* __restrict__ cost,
                                               const float* __restrict__ feat,
                                               const float* __restrict__ w_q,
                                               const float* __restrict__ w_k,
                                               const float* __restrict__ w_v,
                                               const float* __restrict__ gniw,
                                               unsigned short* __restrict__ qr,
                                               float2* __restrict__ part1,
                                               float* __restrict__ pkv) {
    __shared__ float wqg[En * Cn];
    const int b = blockIdx.y, tid = threadIdx.x;
    for (int i = tid; i < En * Cn; i += 256) wqg[i] = w_q[i] * gniw[i & 31];
    __syncthreads();
    const int n = blockIdx.x * 256 + tid;
    const int d = n >> 11, r = n & 2047, hq = r >> 6, wq = r & 63;
    const float* base = cost + (size_t)b * PERB + (size_t)d * 8192 + (hq * 2) * Wn + wq * 2;
    float s = 0.f, ss = 0.f;
    float q[En];
#pragma unroll
    for (int e = 0; e < En; ++e) q[e] = 0.f;
#pragma unroll 4
    for (int c = 0; c < Cn; ++c) {
        const float* src = base + (size_t)c * DHW;
        float2 t0 = *reinterpret_cast<const float2*>(src);
        float2 t1 = *reinterpret_cast<const float2*>(src + Wn);
        float ps = t0.x + t0.y + t1.x + t1.y;
        s += ps;
        ss += t0.x * t0.x + t0.y * t0.y + t1.x * t1.x + t1.y * t1.y;
        float pv = 0.25f * ps;
#pragma unroll
        for (int e = 0; e < En; ++e) q[e] += wqg[e * Cn + c] * pv;
    }
#pragma unroll
    for (int e = 0; e < En; ++e) qr[(size_t)(b * En + e) * NPB + n] = bf16b(q[e]);
    float2 rp = block_red2(s, ss);
    if (!tid) part1[b * 2048 + blockIdx.x] = rp;

    // K/V partials: 64 blocks (y==0, x<64): x -> (batch kb = x>>4, chunk ch = x&15)
    if (b == 0 && blockIdx.x < 64 && tid < NS) {
        const int kb = blockIdx.x >> 4, ch = blockIdx.x & 15, sI = tid;
        float f[16];
#pragma unroll
        for (int j = 0; j < 16; ++j) f[j] = feat[(size_t)(kb * 256 + ch * 16 + j) * NS + sI];
        float kk[En], vv[En];
#pragma unroll
        for (int e = 0; e < En; ++e) { kk[e] = 0.f; vv[e] = 0.f; }
#pragma unroll
        for (int j = 0; j < 16; ++j) {
            const int c = ch * 16 + j;
#pragma unroll
            for (int e = 0; e < En; ++e) {
                kk[e] += w_k[e * 256 + c] * f[j];
                vv[e] += w_v[e * 256 + c] * f[j];
            }
        }
#pragma unroll
        for (int e = 0; e < En; ++e) {
            pkv[((size_t)(kb * 16 + ch) * 24 + e) * 128 + sI] = kk[e];
            pkv[((size_t)(kb * 16 + ch) * 24 + 12 + e) * 128 + sI] = vv[e];
        }
    }
}

// ---------- K2: blocks 0-3 finalize stats1; blocks 4-7 combine K/V + kscale ----------
__global__ __launch_bounds__(256) void k_mid(const float2* __restrict__ part1,
                                             const float* __restrict__ pkv,
                                             float2* __restrict__ st1,
                                             float* __restrict__ KB, float* __restrict__ VB,
                                             float* __restrict__ ksc) {
    const int blk = blockIdx.x, tid = threadIdx.x;
    if (blk < 4) {
        float s = 0.f, ss = 0.f;
        for (int i = tid; i < 384; i += 256) {
            float2 v = part1[blk * 2048 + i];
            s += v.x; ss += v.y;
        }
        float2 t = block_red2(s, ss);
        if (!tid) {
            float m = t.x / (float)PERB;
            float var = t.y / (float)PERB - m * m;
            st1[blk] = make_float2(m, rsqrtf(var + EPS));
        }
    } else {
        const int b = blk - 4;
        __shared__ float wmax[2];
        if (tid < NS) {
            const int s = tid;
            float kk[En], vv[En];
#pragma unroll
            for (int e = 0; e < En; ++e) { kk[e] = 0.f; vv[e] = 0.f; }
            for (int ch = 0; ch < 16; ++ch) {
                const float* p = pkv + ((size_t)(b * 16 + ch) * 24) * 128 + s;
#pragma unroll
                for (int e = 0; e < En; ++e) {
                    kk[e] += p[e * 128];
                    vv[e] += p[(12 + e) * 128];
                }
            }
            float n2 = 0.f;
#pragma unroll
            for (int e = 0; e < En; ++e) {
                KB[(size_t)(b * NS + s) * En + e] = kk[e];
                VB[(size_t)(b * NS + s) * En + e] = vv[e];
                n2 += kk[e] * kk[e];
            }
            float nn = sqrtf(n2);
#pragma unroll
            for (int off = 32; off; off >>= 1) nn = fmaxf(nn, __shfl_down(nn, off, 64));
            if (!(tid & 63)) wmax[tid >> 6] = nn;
        }
        __syncthreads();
        if (!tid) ksc[b] = fmaxf(wmax[0], wmax[1]);
    }
}

// ---------- K3: attention (one-pass UB softmax) + out-projection -> Z (bf16) ----------
__global__ __launch_bounds__(256) void k_attn(const unsigned short* __restrict__ qr,
                                              const float* __restrict__ KB,
                                              const float* __restrict__ VB,
                                              const float* __restrict__ w_q,
                                              const float* __restrict__ gniw,
                                              const float* __restrict__ gnib,
                                              const float* __restrict__ ksc,
                                              const float2* __restrict__ st1,
                                              const float* __restrict__ w_out,
                                              unsigned short* __restrict__ zb) {
    __shared__ float Ks[NS * En], Vs[NS * En], WOs[Cn * En], QBs[En];
    const int b = blockIdx.y, tid = threadIdx.x;
    for (int i = tid; i < NS * En; i += 256) {
        Ks[i] = KB[(size_t)b * NS * En + i];
        Vs[i] = VB[(size_t)b * NS * En + i];
    }
    for (int i = tid; i < Cn * En; i += 256) WOs[i] = w_out[i];
    float2 s1 = st1[b];
    if (tid < En) {
        float acc = 0.f;
        for (int c = 0; c < Cn; ++c)
            acc += w_q[tid * Cn + c] * (gnib[c] - s1.x * s1.y * gniw[c]);
        QBs[tid] = SQK * acc;
    }
    __syncthreads();
    const int n = blockIdx.x * 256 + tid;
    const float qsc = s1.y * SQK;
    float q[En];
    float qn2 = 0.f;
#pragma unroll
    for (int e = 0; e < En; ++e) {
        q[e] = qsc * b2f(qr[(size_t)(b * En + e) * NPB + n]) + QBs[e];
        qn2 += q[e] * q[e];
    }
    const float ub = sqrtf(qn2) * ksc[b];  // Cauchy-Schwarz >= max logit
    float l = 0.f;
    float o[En];
#pragma unroll
    for (int e = 0; e < En; ++e) o[e] = 0.f;
    for (int s = 0; s < NS; ++s) {
        float dot = 0.f;
#pragma unroll
        for (int e = 0; e < En; ++e) dot += q[e] * Ks[s * En + e];
        float pe = __expf(dot - ub);
        l += pe;
#pragma unroll
        for (int e = 0; e < En; ++e) o[e] += pe * Vs[s * En + e];
    }
    const float inv = 1.0f / l;
    for (int c = 0; c < Cn; ++c) {
        float z = 0.f;
#pragma unroll
        for (int e = 0; e < En; ++e) z += WOs[c * En + e] * o[e];
        zb[(size_t)(b * Cn + c) * NPB + n] = bf16b(z * inv);
    }
}

// ---------- K4: y-stats; one block per (b,c,d) slice; Z slice (bf16) in LDS ----------
__global__ __launch_bounds__(256) void k_ystats(const float* __restrict__ cost,
                                                const unsigned short* __restrict__ zb,
                                                const float* __restrict__ gamma_p,
                                                float2* __restrict__ part2) {
    const int blk = blockIdx.x;  // ((b*32+c)*48+d)
    __shared__ unsigned short zs[HQ * WQ];
    const int tid = threadIdx.x;
    {
        const unsigned int* zsrc = (const unsigned int*)(zb + (size_t)blk * 2048);
        for (int i = tid; i < 1024; i += 256) ((unsigned int*)zs)[i] = zsrc[i];
    }
    __syncthreads();
    const float g = gamma_p[0];
    const f4v* cq = (const f4v*)(cost + (size_t)blk * 8192);
    float s = 0.f, ss = 0.f;
#pragma unroll
    for (int k = 0; k < 8; ++k) {
        int qd = tid + 256 * k;
        int h = qd >> 5, w4 = (qd & 31) << 2;
        f4v cv = cq[qd];
        int h0 = (h - 1) >> 1;
        float wh0 = (h & 1) ? 0.75f : 0.25f;
        int h1 = h0 + 1;
        h0 = h0 < 0 ? 0 : h0; h1 = h1 > HQ - 1 ? HQ - 1 : h1;
        const unsigned short* r0 = zs + h0 * WQ;
        const unsigned short* r1 = zs + h1 * WQ;
#pragma unroll
        for (int j = 0; j < 4; ++j) {
            int w = w4 + j;
            int w0 = (w - 1) >> 1;
            float ww0 = (w & 1) ? 0.75f : 0.25f;
            int w1 = w0 + 1;
            w0 = w0 < 0 ? 0 : w0; w1 = w1 > WQ - 1 ? WQ - 1 : w1;
            float u = wh0 * (ww0 * b2f(r0[w0]) + (1.f - ww0) * b2f(r0[w1])) +
                      (1.f - wh0) * (ww0 * b2f(r1[w0]) + (1.f - ww0) * b2f(r1[w1]));
            float y = cv[j] + g * bf16_rne(u);
            s += y; ss += y * y;
        }
    }
    float2 rp = block_red2(s, ss);
    if (!tid) part2[blk] = rp;
}

// ---------- K5: finalize stats2 ----------
__global__ __launch_bounds__(256) void k_fin2(const float2* __restrict__ part2,
                                              float2* __restrict__ st2) {
    const int b = blockIdx.x, tid = threadIdx.x;
    float s = 0.f, ss = 0.f;
    for (int i = tid; i < 1536; i += 256) {
        float2 v = part2[b * 1536 + i];
        s += v.x; ss += v.y;
    }
    float2 t = block_red2(s, ss);
    if (!tid) {
        float m = t.x / (float)PERB;
        float var = t.y / (float)PERB - m * m;
        st2[b] = make_float2(m, rsqrtf(var + EPS));
    }
}

// ---------- K6: recompute y, final GroupNorm, nontemporal store ----------
__global__ __launch_bounds__(256) void k_final(const float* __restrict__ cost,
                                               const unsigned short* __restrict__ zb,
                                               const float* __restrict__ gamma_p,
                                               const float2* __restrict__ st2,
                                               const float* __restrict__ gow,
                                               const float* __restrict__ gob,
                                               float* __restrict__ out) {
    const int blk = blockIdx.x;
    __shared__ unsigned short zs[HQ * WQ];
    const int tid = threadIdx.x;
    {
        const unsigned int* zsrc = (const unsigned int*)(zb + (size_t)blk * 2048);
        for (int i = tid; i < 1024; i += 256) ((unsigned int*)zs)[i] = zsrc[i];
    }
    __syncthreads();
    const int b = blk / (Cn * Dn);
    const int c = (blk / Dn) % Cn;
    const float g = gamma_p[0];
    float2 st = st2[b];
    const float m = st.x, sc = st.y * gow[c], bi = gob[c];
    const f4v* cq = (const f4v*)(cost + (size_t)blk * 8192);
    f4v* oq = (f4v*)(out + (size_t)blk * 8192);
#pragma unroll
    for (int k = 0; k < 8; ++k) {
        int qd = tid + 256 * k;
        int h = qd >> 5, w4 = (qd & 31) << 2;
        f4v cv = cq[qd];
        int h0 = (h - 1) >> 1;
        float wh0 = (h & 1) ? 0.75f : 0.25f;
        int h1 = h0 + 1;
        h0 = h0 < 0 ? 0 : h0; h1 = h1 > HQ - 1 ? HQ - 1 : h1;
        const unsigned short* r0 = zs + h0 * WQ;
        const unsigned short* r1 = zs + h1 * WQ;
        f4v ov;
#pragma unroll
        for (int j = 0; j < 4; ++j) {
            int w = w4 + j;
            int w0 = (w - 1) >> 1;
            float ww0 = (w & 1) ? 0.75f : 0.25f;
            int w1 = w0 + 1;
            w0 = w0 < 0 ? 0 : w0; w1 = w1 > WQ - 1 ? WQ - 1 : w1;
            float u = wh0 * (ww0 * b2f(r0[w0]) + (1.f - ww0) * b2f(r0[w1])) +
                      (1.f - wh0) * (ww0 * b2f(r1[w0]) + (1.f - ww0) * b2f(r1[w1]));
            float y = cv[j] + g * bf16_rne(u);
            ov[j] = (y - m) * sc + bi;
        }
        __builtin_nontemporal_store(ov, oq + qd);
    }
}

extern "C" void kernel_launch(void* const* d_in, const int* in_sizes, int n_in,
                              void* d_out, int out_size, void* d_ws, size_t ws_size,
                              hipStream_t stream) {
    const float* cost  = (const float*)d_in[0];
    const float* feat  = (const float*)d_in[1];
    const float* w_q   = (const float*)d_in[2];
    const float* w_k   = (const float*)d_in[3];
    const float* w_v   = (const float*)d_in[4];
    const float* w_out = (const float*)d_in[5];
    const float* gniw  = (const float*)d_in[6];
    const float* gnib  = (const float*)d_in[7];
    const float* gow   = (const float*)d_in[8];
    const float* gob   = (const float*)d_in[9];
    const float* gamma = (const float*)d_in[10];

    float* ws = (float*)d_ws;
    float* outp = (float*)d_out;

    unsigned short* zb = (unsigned short*)(ws + OFF_Z);
    unsigned short* qr = (unsigned short*)(ws + OFF_QR);
    float2* part1 = (float2*)(ws + OFF_P1);
    float2* part2 = (float2*)(ws + OFF_P2);
    float2* st1 = (float2*)(ws + OFF_ST1);
    float2* st2 = (float2*)(ws + OFF_ST2);
    float* KB  = ws + OFF_KB;
    float* VB  = ws + OFF_VB;
    float* ksc = ws + OFF_KS;
    float* pkv = ws + OFF_PKV;

    k1_pool<<<dim3(384, Bn), 256, 0, stream>>>(cost, feat, w_q, w_k, w_v, gniw, qr, part1, pkv);
    k_mid<<<8, 256, 0, stream>>>(part1, pkv, st1, KB, VB, ksc);
    k_attn<<<dim3(384, Bn), 256, 0, stream>>>(qr, KB, VB, w_q, gniw, gnib, ksc, st1, w_out, zb);
    k_ystats<<<Bn * Cn * Dn, 256, 0, stream>>>(cost, zb, gamma, part2);
    k_fin2<<<Bn, 256, 0, stream>>>(part2, st2);
    k_final<<<Bn * Cn * Dn, 256, 0, stream>>>(cost, zb, gamma, st2, gow, gob, outp);
}